// Round 7
// baseline (246.594 us; speedup 1.0000x reference)
//
#include <hip/hip_runtime.h>
#include <hip/hip_bf16.h>

#define BN    4
#define NN    2048
#define INF   128
#define HH    8
#define HD    16
#define ALPHA 0.2f
#define DECAY 0.1f

// exp2 folding: w2 = log2e * exp(-DECAY*(ct-t)) = exp2(fma(DLOG2E, t, c0)),
// c0 = -DLOG2E*ct + log2(log2e). Then p = exp2(sc * w2).
#define DLOG2E 0.14426950408889634f   // DECAY * log2(e)
#define LLOG2E 0.5287663729448977f    // log2(log2(e))

typedef __attribute__((ext_vector_type(8))) short short8;
typedef __attribute__((ext_vector_type(4))) float float4v;

__device__ __forceinline__ float bf2f(unsigned short u) {
    return __uint_as_float(((unsigned)u) << 16);
}

// ---------------- Kernel 1: fused [max over tm] + [proj h_t/es/ed] ---------
__launch_bounds__(256, 8)
__global__ void k_setup(const float* __restrict__ x,
                        const float* __restrict__ W,
                        const float* __restrict__ a,
                        const float* __restrict__ tm,
                        unsigned* __restrict__ ct,
                        __hip_bfloat16* __restrict__ h_t,
                        float* __restrict__ es, float* __restrict__ ed) {
    if (blockIdx.x < 1024) {
        // ct = max(tm); values >= 0 so u32-compare == f32-compare
        const uint4* p = (const uint4*)tm;
        const int nvec = BN * NN * NN / 4;
        int idx = blockIdx.x * 256 + threadIdx.x;
        const int stride = 1024 * 256;
        unsigned m = 0u;
        for (int i = idx; i < nvec; i += stride) {
            uint4 v = p[i];
            m = max(m, v.x); m = max(m, v.y); m = max(m, v.z); m = max(m, v.w);
        }
        float fm = __uint_as_float(m);
        #pragma unroll
        for (int o = 32; o >= 1; o >>= 1) fm = fmaxf(fm, __shfl_xor(fm, o));
        __shared__ float sm[4];
        if ((threadIdx.x & 63) == 0) sm[threadIdx.x >> 6] = fm;
        __syncthreads();
        if (threadIdx.x == 0) {
            float mm = fmaxf(fmaxf(sm[0], sm[1]), fmaxf(sm[2], sm[3]));
            atomicMax(ct, __float_as_uint(mm));
        }
    } else {
        int bid = blockIdx.x - 1024;          // 0..4095
        int sub = threadIdx.x >> 7;
        int tt  = threadIdx.x & 127;
        int nn  = bid * 2 + sub;              // b*NN+n
        __shared__ float xs[2][INF];
        xs[sub][tt] = x[(size_t)nn * INF + tt];
        __syncthreads();
        int h = tt >> 4, d = tt & 15;
        const float* Wp = W + (h * INF) * HD + d;
        float acc = 0.f;
        #pragma unroll 16
        for (int i = 0; i < INF; i++) acc += xs[sub][i] * Wp[i * HD];
        int b = nn >> 11, n = nn & 2047;
        h_t[((size_t)((b * HH + h) * HD + d)) * NN + n] = __float2bfloat16(acc);
        float s  = acc * a[h * 2 * HD + d];
        float dd = acc * a[h * 2 * HD + HD + d];
        #pragma unroll
        for (int o = 8; o >= 1; o >>= 1) { s += __shfl_xor(s, o); dd += __shfl_xor(dd, o); }
        if (d == 0) {
            es[(b * HH + h) * NN + n] = s;
            ed[(b * HH + h) * NN + n] = dd;
        }
    }
}

// ---------------- Kernel 2: fused scores + partial softmax + PV (MFMA) -----
// grid: B * 2(j-half) * 128(i-tile) = 1024 blocks; block: 8 waves, wave=head.
// LDS tw tile is XOR-SWIZZLED at 16B-block granularity (blk ^ (row&7), row
// stride 128 floats, no pad): both the cooperative writes and the per-lane
// b128 fragment reads are exactly 2-way per bank-group (= free, m136).
// Row sums come from a second MFMA against an all-ones B fragment (no VALU).
// A-fragments are packed with round-half-up (u+0x8000)>>16 via v_perm.
__launch_bounds__(512, 8)
__global__ void k_attn(const int* __restrict__ adj,
                       const float* __restrict__ tm,
                       const __hip_bfloat16* __restrict__ h_t,
                       const float* __restrict__ es, const float* __restrict__ ed,
                       const unsigned* __restrict__ ctp,
                       float* __restrict__ pacc, float* __restrict__ pl) {
    int t    = threadIdx.x;
    int w    = t >> 6;          // head
    int lane = t & 63;
    int q    = lane >> 4;       // quad 0..3
    int im   = lane & 15;       // i within tile / d for B-frag
    int bx   = blockIdx.x;
    int b    = bx >> 8;
    int half = (bx >> 7) & 1;
    int i0   = (bx & 127) << 4;
    int i    = i0 + im;
    int jb   = half << 10;      // j-half base
    const int R = 8;            // 8 rounds x 128 j

    __shared__ float tws[2][16 * 128];   // swizzled, double-buffered (16 KB)

    float ctv = __uint_as_float(*ctp);
    float c0  = fmaf(-DLOG2E, ctv, LLOG2E);
    float es_i = es[(b * HH + w) * NN + i];

    const float* ed_p = ed + (size_t)(b * HH + w) * NN + jb + q * 8;
    const __hip_bfloat16* ht_p = h_t + ((size_t)((b * HH + w) * HD + im)) * NN + jb + q * 8;

    // staging map: 512 threads x 4 floats = 16 rows x 32 16B-blocks
    int srow = t >> 5;                       // 0..15
    int sblk = t & 31;                       // logical 16B block
    int soff = srow * 128 + ((sblk ^ (srow & 7)) << 2);   // swizzled float idx
    const int*   adj_s = adj + ((size_t)(b * NN + i0 + srow)) * NN + jb + (sblk << 2);
    const float* tm_s  = tm  + ((size_t)(b * NN + i0 + srow)) * NN + jb + (sblk << 2);

    // per-lane swizzled read offsets (two b128 per chunk)
    // logical blocks: blk0 = c4*8 + 2q, blk1 = blk0 + 1
    int rbase = im * 128;
    int rx    = im & 7;

    // all-ones bf16 B fragment for row sums
    union { uint4 u; short8 v; } ones;
    ones.u = make_uint4(0x3F803F80u, 0x3F803F80u, 0x3F803F80u, 0x3F803F80u);

    float4v acc  = {0.f, 0.f, 0.f, 0.f};
    float4v accl = {0.f, 0.f, 0.f, 0.f};

    // prologue: stage round 0, prefetch round 1
    int4   pa = *(const int4*)(adj_s);
    float4 pt = *(const float4*)(tm_s);
    {
        float w0 = (pa.x != 0) ? exp2f(fmaf(DLOG2E, pt.x, c0)) : 0.f;
        float w1 = (pa.y != 0) ? exp2f(fmaf(DLOG2E, pt.y, c0)) : 0.f;
        float w2 = (pa.z != 0) ? exp2f(fmaf(DLOG2E, pt.z, c0)) : 0.f;
        float w3 = (pa.w != 0) ? exp2f(fmaf(DLOG2E, pt.w, c0)) : 0.f;
        *(float4*)&tws[0][soff] = make_float4(w0, w1, w2, w3);
    }
    pa = *(const int4*)(adj_s + 128);
    pt = *(const float4*)(tm_s + 128);
    __syncthreads();

    for (int r = 0; r < R; r++) {
        int cur = r & 1;
        if (r + 1 < R) {
            float w0 = (pa.x != 0) ? exp2f(fmaf(DLOG2E, pt.x, c0)) : 0.f;
            float w1 = (pa.y != 0) ? exp2f(fmaf(DLOG2E, pt.y, c0)) : 0.f;
            float w2 = (pa.z != 0) ? exp2f(fmaf(DLOG2E, pt.z, c0)) : 0.f;
            float w3 = (pa.w != 0) ? exp2f(fmaf(DLOG2E, pt.w, c0)) : 0.f;
            *(float4*)&tws[cur ^ 1][soff] = make_float4(w0, w1, w2, w3);
            if (r + 2 < R) {
                pa = *(const int4*)(adj_s + (r + 2) * 128);
                pt = *(const float4*)(tm_s + (r + 2) * 128);
            }
        }
        #pragma unroll
        for (int c4 = 0; c4 < 4; c4++) {
            int blk0 = c4 * 8 + 2 * q;
            float4 w01 = *(const float4*)&tws[cur][rbase + ((blk0 ^ rx) << 2)];
            float4 w23 = *(const float4*)&tws[cur][rbase + (((blk0 + 1) ^ rx) << 2)];
            int jglob = r * 128 + c4 * 32;
            float4 e0 = *(const float4*)(ed_p + jglob);
            float4 e1 = *(const float4*)(ed_p + jglob + 4);
            uint4  hv = *(const uint4*)(ht_p + jglob);

            float wv[8] = {w01.x, w01.y, w01.z, w01.w, w23.x, w23.y, w23.z, w23.w};
            float ev[8] = {e0.x, e0.y, e0.z, e0.w, e1.x, e1.y, e1.z, e1.w};

            unsigned u[8];
            #pragma unroll
            for (int k = 0; k < 8; k++) {
                float s0 = es_i + ev[k];
                float sc = fmaxf(s0, ALPHA * s0);      // leaky_relu
                float pv = exp2f(sc * wv[k]);          // w pre-scaled by log2e
                unsigned b16 = __float_as_uint(pv) + 0x8000u;  // round-half-up
                u[k] = (wv[k] > 0.f) ? b16 : 0u;       // masked -> 0
            }
            union { uint4 w; short8 v; } af;
            af.w.x = __builtin_amdgcn_perm(u[1], u[0], 0x07060302u);
            af.w.y = __builtin_amdgcn_perm(u[3], u[2], 0x07060302u);
            af.w.z = __builtin_amdgcn_perm(u[5], u[4], 0x07060302u);
            af.w.w = __builtin_amdgcn_perm(u[7], u[6], 0x07060302u);

            union { uint4 u; short8 v; } bf;
            bf.u = hv;
            acc  = __builtin_amdgcn_mfma_f32_16x16x32_bf16(af.v, bf.v, acc, 0, 0, 0);
            accl = __builtin_amdgcn_mfma_f32_16x16x32_bf16(af.v, ones.v, accl, 0, 0, 0);
        }
        __syncthreads();
    }

    // D layout: col = lane&15, row = q*4 + reg. accl cols are all identical,
    // so accl[r] IS the row sum l(q*4+r) -- no cross-lane reduction needed.
    float* pb = pacc + ((size_t)bx * 8 + w) * 256;
    #pragma unroll
    for (int r = 0; r < 4; r++) pb[(q * 4 + r) * 16 + im] = acc[r];
    if (im == 0) {
        #pragma unroll
        for (int r = 0; r < 4; r++) pl[(size_t)bx * 128 + w * 16 + q * 4 + r] = accl[r];
    }
}

// ---------------- Kernel 3: combine j-halves + normalize + ELU -------------
__launch_bounds__(256, 8)
__global__ void k_fin(const float* __restrict__ pacc, const float* __restrict__ pl,
                      float* __restrict__ out) {
    int o = blockIdx.x * 256 + threadIdx.x;   // B*N*H*HD = 1,048,576
    int b   = o >> 18;
    int rem = o & 262143;
    int i   = rem >> 7;
    int hd  = rem & 127;
    int h   = hd >> 4;
    int d   = hd & 15;
    int it  = i >> 4;
    int row = i & 15;
    int blk0 = (b * 2 + 0) * 128 + it;
    int blk1 = blk0 + 128;
    float a0 = pacc[((size_t)blk0 * 8 + h) * 256 + row * 16 + d];
    float a1 = pacc[((size_t)blk1 * 8 + h) * 256 + row * 16 + d];
    float l  = pl[(size_t)blk0 * 128 + h * 16 + row]
             + pl[(size_t)blk1 * 128 + h * 16 + row];
    float v = (a0 + a1) / l;
    v = (v > 0.f) ? v : expm1f(v);   // ELU
    out[o] = v;
}

extern "C" void kernel_launch(void* const* d_in, const int* in_sizes, int n_in,
                              void* d_out, int out_size, void* d_ws, size_t ws_size,
                              hipStream_t stream) {
    const float* x   = (const float*)d_in[0];
    const int*   adj = (const int*)d_in[1];
    const float* tm  = (const float*)d_in[2];
    const float* W   = (const float*)d_in[3];
    const float* a   = (const float*)d_in[4];
    float* out = (float*)d_out;

    float* wsf = (float*)d_ws;
    unsigned* ct = (unsigned*)wsf;
    float* es = wsf + 64;                                    // 65,536
    float* ed = es + BN * HH * NN;                           // 65,536
    __hip_bfloat16* h_t = (__hip_bfloat16*)(ed + BN * HH * NN);  // 1,048,576 bf16
    float* pacc = (float*)(h_t + BN * HH * HD * NN);         // 2,097,152
    float* pl   = pacc + 1024 * 2048;                        // 131,072

    hipMemsetAsync(d_ws, 0, 4, stream);                      // ct = 0.0f
    k_setup<<<1024 + 4096, 256, 0, stream>>>(x, W, a, tm, ct, h_t, es, ed);
    k_attn <<<BN * 2 * (NN / 16), 512, 0, stream>>>(adj, tm, h_t, es, ed, ct, pacc, pl);
    k_fin  <<<(BN * NN * HH * HD) / 256, 256, 0, stream>>>(pacc, pl, out);
}

// Round 8
// 235.738 us; speedup vs baseline: 1.0460x; 1.0460x over previous
//
#include <hip/hip_runtime.h>
#include <hip/hip_bf16.h>

#define BN    4
#define NN    2048
#define INF   128
#define HH    8
#define HD    16
#define ALPHA 0.2f
#define DECAY 0.1f

// exp2 folding: w2 = log2e * exp(-DECAY*(ct-t)) = exp2(fma(DLOG2E, t, c0)),
// c0 = -DLOG2E*ct + log2(log2e). Then p = exp2(sc * w2).
#define DLOG2E 0.14426950408889634f   // DECAY * log2(e)
#define LLOG2E 0.5287663729448977f    // log2(log2(e))

typedef __attribute__((ext_vector_type(8))) short short8;
typedef __attribute__((ext_vector_type(4))) float float4v;

// ---------------- Kernel 1: fused [max over tm] + [proj h_t/es/ed] ---------
__launch_bounds__(256, 8)
__global__ void k_setup(const float* __restrict__ x,
                        const float* __restrict__ W,
                        const float* __restrict__ a,
                        const float* __restrict__ tm,
                        unsigned* __restrict__ ct,
                        __hip_bfloat16* __restrict__ h_t,
                        float* __restrict__ es, float* __restrict__ ed) {
    if (blockIdx.x < 1024) {
        // ct = max(tm); values >= 0 so u32-compare == f32-compare
        const uint4* p = (const uint4*)tm;
        const int nvec = BN * NN * NN / 4;
        int idx = blockIdx.x * 256 + threadIdx.x;
        const int stride = 1024 * 256;
        unsigned m = 0u;
        for (int i = idx; i < nvec; i += stride) {
            uint4 v = p[i];
            m = max(m, v.x); m = max(m, v.y); m = max(m, v.z); m = max(m, v.w);
        }
        float fm = __uint_as_float(m);
        #pragma unroll
        for (int o = 32; o >= 1; o >>= 1) fm = fmaxf(fm, __shfl_xor(fm, o));
        __shared__ float sm[4];
        if ((threadIdx.x & 63) == 0) sm[threadIdx.x >> 6] = fm;
        __syncthreads();
        if (threadIdx.x == 0) {
            float mm = fmaxf(fmaxf(sm[0], sm[1]), fmaxf(sm[2], sm[3]));
            atomicMax(ct, __float_as_uint(mm));
        }
    } else {
        int bid = blockIdx.x - 1024;          // 0..4095
        int sub = threadIdx.x >> 7;
        int tt  = threadIdx.x & 127;
        int nn  = bid * 2 + sub;              // b*NN+n
        __shared__ float xs[2][INF];
        xs[sub][tt] = x[(size_t)nn * INF + tt];
        __syncthreads();
        int h = tt >> 4, d = tt & 15;
        const float* Wp = W + (h * INF) * HD + d;
        float acc = 0.f;
        #pragma unroll 16
        for (int i = 0; i < INF; i++) acc += xs[sub][i] * Wp[i * HD];
        int b = nn >> 11, n = nn & 2047;
        h_t[((size_t)((b * HH + h) * HD + d)) * NN + n] = __float2bfloat16(acc);
        float s  = acc * a[h * 2 * HD + d];
        float dd = acc * a[h * 2 * HD + HD + d];
        #pragma unroll
        for (int o = 8; o >= 1; o >>= 1) { s += __shfl_xor(s, o); dd += __shfl_xor(dd, o); }
        if (d == 0) {
            es[(b * HH + h) * NN + n] = s;
            ed[(b * HH + h) * NN + n] = dd;
        }
    }
}

// ---------------- Kernel 2: fused scores + softmax + PV (MFMA), one pass ---
// grid: B * 128 i-tiles = 512 blocks; block: 8 waves, wave = head.
// Per 128-j round the block stages head-independent masked
// w2 = log2e*exp(-d*(ct-t)) into an XOR-swizzled double-buffered LDS tile
// (one barrier per round). Row-sum denominators come from a second MFMA
// against an all-ones B fragment, so accl[r] IS l(row) with zero cross-lane
// traffic. A-fragments packed via round-half-up + v_perm.
// launch_bounds (512,4): 128-VGPR budget -- round 7's (512,8) 64-VGPR cap
// caused hot-loop scratch spills (WRITE_SIZE 8.7->27 MB); occupancy 35% vs
// 72% measured neutral (r5 vs r6), so the register room is free.
__launch_bounds__(512, 4)
__global__ void k_attn(const int* __restrict__ adj,
                       const float* __restrict__ tm,
                       const __hip_bfloat16* __restrict__ h_t,
                       const float* __restrict__ es, const float* __restrict__ ed,
                       const unsigned* __restrict__ ctp,
                       float* __restrict__ out) {
    int t    = threadIdx.x;
    int w    = t >> 6;          // head
    int lane = t & 63;
    int q    = lane >> 4;       // quad 0..3
    int im   = lane & 15;       // i within tile / d for B-frag
    int bx   = blockIdx.x;
    int b    = bx >> 7;
    int i0   = (bx & 127) << 4;
    int i    = i0 + im;
    const int R = 16;           // 16 rounds x 128 j = 2048

    __shared__ float tws[2][16 * 128];   // swizzled, double-buffered (16 KB)

    float ctv = __uint_as_float(*ctp);
    float c0  = fmaf(-DLOG2E, ctv, LLOG2E);
    float es_i = es[(b * HH + w) * NN + i];

    const float* ed_p = ed + (size_t)(b * HH + w) * NN + q * 8;
    const __hip_bfloat16* ht_p = h_t + ((size_t)((b * HH + w) * HD + im)) * NN + q * 8;

    // staging map: 512 threads x 4 floats = 16 rows x 32 16B-blocks
    int srow = t >> 5;                       // 0..15
    int sblk = t & 31;                       // logical 16B block
    int soff = srow * 128 + ((sblk ^ (srow & 7)) << 2);   // swizzled float idx
    const int*   adj_s = adj + ((size_t)(b * NN + i0 + srow)) * NN + (sblk << 2);
    const float* tm_s  = tm  + ((size_t)(b * NN + i0 + srow)) * NN + (sblk << 2);

    // per-lane swizzled read base
    int rbase = im * 128;
    int rx    = im & 7;

    // all-ones bf16 B fragment for row sums
    union { uint4 u; short8 v; } ones;
    ones.u = make_uint4(0x3F803F80u, 0x3F803F80u, 0x3F803F80u, 0x3F803F80u);

    float4v acc  = {0.f, 0.f, 0.f, 0.f};
    float4v accl = {0.f, 0.f, 0.f, 0.f};

    // prologue: stage round 0, prefetch round 1
    int4   pa = *(const int4*)(adj_s);
    float4 pt = *(const float4*)(tm_s);
    {
        float w0 = (pa.x != 0) ? exp2f(fmaf(DLOG2E, pt.x, c0)) : 0.f;
        float w1 = (pa.y != 0) ? exp2f(fmaf(DLOG2E, pt.y, c0)) : 0.f;
        float w2 = (pa.z != 0) ? exp2f(fmaf(DLOG2E, pt.z, c0)) : 0.f;
        float w3 = (pa.w != 0) ? exp2f(fmaf(DLOG2E, pt.w, c0)) : 0.f;
        *(float4*)&tws[0][soff] = make_float4(w0, w1, w2, w3);
    }
    pa = *(const int4*)(adj_s + 128);
    pt = *(const float4*)(tm_s + 128);
    __syncthreads();

    for (int r = 0; r < R; r++) {
        int cur = r & 1;
        if (r + 1 < R) {
            float w0 = (pa.x != 0) ? exp2f(fmaf(DLOG2E, pt.x, c0)) : 0.f;
            float w1 = (pa.y != 0) ? exp2f(fmaf(DLOG2E, pt.y, c0)) : 0.f;
            float w2 = (pa.z != 0) ? exp2f(fmaf(DLOG2E, pt.z, c0)) : 0.f;
            float w3 = (pa.w != 0) ? exp2f(fmaf(DLOG2E, pt.w, c0)) : 0.f;
            *(float4*)&tws[cur ^ 1][soff] = make_float4(w0, w1, w2, w3);
            if (r + 2 < R) {
                pa = *(const int4*)(adj_s + (r + 2) * 128);
                pt = *(const float4*)(tm_s + (r + 2) * 128);
            }
        }
        #pragma unroll
        for (int c4 = 0; c4 < 4; c4++) {
            int blk0 = c4 * 8 + 2 * q;
            float4 w01 = *(const float4*)&tws[cur][rbase + ((blk0 ^ rx) << 2)];
            float4 w23 = *(const float4*)&tws[cur][rbase + (((blk0 + 1) ^ rx) << 2)];
            int jglob = r * 128 + c4 * 32;
            float4 e0 = *(const float4*)(ed_p + jglob);
            float4 e1 = *(const float4*)(ed_p + jglob + 4);
            uint4  hv = *(const uint4*)(ht_p + jglob);

            float wv[8] = {w01.x, w01.y, w01.z, w01.w, w23.x, w23.y, w23.z, w23.w};
            float ev[8] = {e0.x, e0.y, e0.z, e0.w, e1.x, e1.y, e1.z, e1.w};

            unsigned u[8];
            #pragma unroll
            for (int k = 0; k < 8; k++) {
                float s0 = es_i + ev[k];
                float sc = fmaxf(s0, ALPHA * s0);      // leaky_relu
                float pv = exp2f(sc * wv[k]);          // w pre-scaled by log2e
                unsigned b16 = __float_as_uint(pv) + 0x8000u;  // round-half-up
                u[k] = (wv[k] > 0.f) ? b16 : 0u;       // masked -> 0
            }
            union { uint4 w; short8 v; } af;
            af.w.x = __builtin_amdgcn_perm(u[1], u[0], 0x07060302u);
            af.w.y = __builtin_amdgcn_perm(u[3], u[2], 0x07060302u);
            af.w.z = __builtin_amdgcn_perm(u[5], u[4], 0x07060302u);
            af.w.w = __builtin_amdgcn_perm(u[7], u[6], 0x07060302u);

            union { uint4 u; short8 v; } bf;
            bf.u = hv;
            acc  = __builtin_amdgcn_mfma_f32_16x16x32_bf16(af.v, bf.v, acc, 0, 0, 0);
            accl = __builtin_amdgcn_mfma_f32_16x16x32_bf16(af.v, ones.v, accl, 0, 0, 0);
        }
        __syncthreads();
    }

    // D layout: col = lane&15, row = q*4 + reg. accl cols all equal l(row),
    // so normalize + ELU + store directly -- no cross-lane traffic at all.
    #pragma unroll
    for (int r = 0; r < 4; r++) {
        int row = q * 4 + r;
        float v = acc[r] / accl[r];
        v = (v > 0.f) ? v : expm1f(v);   // ELU (alpha=1)
        out[((size_t)(b * NN + i0 + row)) * (HH * HD) + w * HD + im] = v;
    }
}

extern "C" void kernel_launch(void* const* d_in, const int* in_sizes, int n_in,
                              void* d_out, int out_size, void* d_ws, size_t ws_size,
                              hipStream_t stream) {
    const float* x   = (const float*)d_in[0];
    const int*   adj = (const int*)d_in[1];
    const float* tm  = (const float*)d_in[2];
    const float* W   = (const float*)d_in[3];
    const float* a   = (const float*)d_in[4];
    float* out = (float*)d_out;

    float* wsf = (float*)d_ws;
    unsigned* ct = (unsigned*)wsf;
    float* es = wsf + 64;                                    // 65,536
    float* ed = es + BN * HH * NN;                           // 65,536
    __hip_bfloat16* h_t = (__hip_bfloat16*)(ed + BN * HH * NN);  // 1,048,576 bf16

    hipMemsetAsync(d_ws, 0, 4, stream);                      // ct = 0.0f
    k_setup<<<1024 + 4096, 256, 0, stream>>>(x, W, a, tm, ct, h_t, es, ed);
    k_attn <<<BN * (NN / 16), 512, 0, stream>>>(adj, tm, h_t, es, ed, ct, out);
}